// Round 8
// baseline (734.033 us; speedup 1.0000x reference)
//
#include <hip/hip_runtime.h>

#define E 1024
#define H 4096
#define NLAYER 24
#define V 50277
#define NB 256
#define NT 1024
#define NWAVE 4096
#define LN_EPS 1e-5f

typedef unsigned long long u64;

// ---- LDS float offsets (dynamic shared, ~156 KB) ----
// R1: A k/v/r rows (12 waves x 1024) <-> C fkw rows (16 x 1024), wave-private
// R2: B ow chunks (16 x 256, front 16KB) <-> D fvw chunks (16 x 1024)
#define R1_OFF   0
#define R2_OFF   16384
#define OFF_X    32768
#define OFF_SX   33792
#define POOL     34816   // xk|xv|xr|wkv (A/B); fxk = pool[0:1024) (C); fk = pool[0:4096) (D)
#define OFF_FXR  38912
#define OFF_RED  39936   // 32
#define OFF_PART 39968   // 16
#define OFF_FR   39984   // 4
#define SMEM_FLOATS 39988

struct Params {
  const float* emb;   const float* ln0_w; const float* ln0_b;
  const float* ln1_w; const float* ln1_b;
  const float* tmk;   const float* tmv;   const float* tmr;
  const float* tf;    const float* td;
  const float* kw;    const float* vw;    const float* rw;  const float* ow;
  const float* ln2_w; const float* ln2_b;
  const float* ftmk;  const float* ftmr;
  const float* fkw;   const float* fvw;   const float* frw;
  const float* lnow;  const float* lnob;  const float* headw;
  const float* st;    const int* tok;
  float* out; float* ws;
};

// ---- tagged 8-byte dataflow handoff (relaxed agent scope) ----
__device__ __forceinline__ void stg_tag(u64* p, float v, unsigned tag) {
  u64 w = ((u64)__float_as_uint(v) << 32) | (u64)tag;
  __hip_atomic_store(p, w, __ATOMIC_RELAXED, __HIP_MEMORY_SCOPE_AGENT);
}
__device__ __forceinline__ u64 ld_tag(const u64* p) {
  return __hip_atomic_load(p, __ATOMIC_RELAXED, __HIP_MEMORY_SCOPE_AGENT);
}
__device__ __forceinline__ float poll_tag(const u64* p, unsigned tag) {
  u64 w = ld_tag(p);
  while ((unsigned)w != tag) { __builtin_amdgcn_s_sleep(2); w = ld_tag(p); }
  return __uint_as_float((unsigned)(w >> 32));
}
__device__ __forceinline__ void poll3(const u64* a, const u64* b, const u64* c,
                                      unsigned tag, float& x, float& y, float& z) {
  u64 wa = ld_tag(a), wb = ld_tag(b), wc = ld_tag(c);
  while ((unsigned)wa != tag) { __builtin_amdgcn_s_sleep(2); wa = ld_tag(a); }
  while ((unsigned)wb != tag) { __builtin_amdgcn_s_sleep(2); wb = ld_tag(b); }
  while ((unsigned)wc != tag) { __builtin_amdgcn_s_sleep(2); wc = ld_tag(c); }
  x = __uint_as_float((unsigned)(wa >> 32));
  y = __uint_as_float((unsigned)(wb >> 32));
  z = __uint_as_float((unsigned)(wc >> 32));
}

// wait for this wave's outstanding vmem (incl. global_load_lds DMAs)
__device__ __forceinline__ void wait_pf() {
  asm volatile("s_waitcnt vmcnt(0)" ::: "memory");
}

// zero-VGPR global->LDS DMA: 64 lanes x 16 B = 1 KB per call.
__device__ __forceinline__ void gload_lds16(const float* g, float* l) {
  __builtin_amdgcn_global_load_lds(
      (const __attribute__((address_space(1))) unsigned int*)(g),
      (__attribute__((address_space(3))) unsigned int*)(l), 16, 0, 0);
}
__device__ __forceinline__ void pf_row4k(const float* row, float* dst, int lane) {
#pragma unroll
  for (int c = 0; c < 4; ++c)
    gload_lds16(row + c * 256 + lane * 4, dst + c * 256);
}

__device__ __forceinline__ float warp_sum(float v) {
#pragma unroll
  for (int off = 32; off; off >>= 1) v += __shfl_down(v, off);
  return v;
}

// fused (sum, sumsq) block reduction; red = 32-float LDS scratch
__device__ float2 block_sum2(float a, float b, float* red) {
#pragma unroll
  for (int off = 32; off; off >>= 1) { a += __shfl_xor(a, off); b += __shfl_xor(b, off); }
  const int wid = threadIdx.x >> 6, lane = threadIdx.x & 63;
  if (lane == 0) { red[wid] = a; red[16 + wid] = b; }
  __syncthreads();
  if (wid == 0) {
    float s1 = (lane < 16) ? red[lane] : 0.f;
    float s2 = (lane < 16) ? red[16 + lane] : 0.f;
#pragma unroll
    for (int off = 8; off; off >>= 1) { s1 += __shfl_down(s1, off); s2 += __shfl_down(s2, off); }
    if (lane == 0) { red[0] = s1; red[16] = s2; }
  }
  __syncthreads();
  return make_float2(red[0], red[16]);
}

__device__ __forceinline__ float dot4(float4 a, float4 b) {
  return a.x * b.x + a.y * b.y + a.z * b.z + a.w * b.w;
}

__device__ __forceinline__ float dotlds(const float* wrow, const float* vec, int lane) {
  const float4* w4 = (const float4*)wrow;
  const float4* v4 = (const float4*)vec;
  float acc = 0.f;
#pragma unroll
  for (int p = 0; p < 4; ++p)
    acc += dot4(w4[lane + p * 64], v4[lane + p * 64]);
  return warp_sum(acc);
}

__device__ __forceinline__ float dot1024(const float* __restrict__ Wrow,
                                         const float* vec, int lane) {
  const float4* W4 = (const float4*)Wrow;
  const float4* v4 = (const float4*)vec;
  float acc = 0.f;
#pragma unroll
  for (int p = 0; p < 4; ++p)
    acc += dot4(W4[lane + p * 64], v4[lane + p * 64]);
  return warp_sum(acc);
}

__global__ __launch_bounds__(NT, 1) void rwkv_kernel(Params p) {
  const int tid = threadIdx.x, bid = blockIdx.x;
  const int lane = tid & 63, wid = tid >> 6;
  const int gw = bid * 16 + wid;          // 0..4095

  extern __shared__ float smem[];
  float* r1    = smem + R1_OFF;
  float* r2    = smem + R2_OFF;
  float* s_x   = smem + OFF_X;
  float* s_sx  = smem + OFF_SX;
  float* pool  = smem + POOL;
  float* s_xk  = pool;
  float* s_xv  = pool + 1024;
  float* s_xr  = pool + 2048;
  float* s_wkv = pool + 3072;
  float* s_fxk = pool;                    // phase C (A's xk dead)
  float* s_fk  = pool;                    // phase D (4096; gated by fk-poll)
  float* s_fxr = smem + OFF_FXR;
  float* s_red = smem + OFF_RED;
  float* s_part= smem + OFF_PART;
  float* s_fr  = smem + OFF_FR;

  // tagged dataflow arrays in ws, parity double-buffered
  u64* tws = (u64*)p.ws;
  u64* tk  = tws;             // [2][E]
  u64* tv  = tws + 2 * E;
  u64* tr  = tws + 4 * E;
  u64* tsx = tws + 6 * E;
  u64* tx  = tws + 8 * E;
  u64* tfk = tws + 10 * E;    // [2][H]

  float* out_st = p.out + V;
  const int token = p.tok[0];

  // wave->row mappings (constant across layers)
  const bool hasA = wid < 12;             // 256 x 12 = 3072 k/v/r rows
  const int rA = bid * 12 + wid;
  const int matA = rA >> 10, rmA = rA & (E - 1);
  const int kcB = wid & 3, rowB = bid * 4 + (wid >> 2);
  const int kcD = wid & 3, rowD = bid * 4 + (wid >> 2);
  float* wA = r1 + wid * 1024;            // wave-private (A rows / C fkw rows)
  float* wB = r2 + wid * 256;             // B ow chunk
  float* wD = r2 + wid * 1024;            // D fvw chunk

  // ---- initial prefetch: A(0) + B(0) ----
  if (hasA) {
    const float* W = (matA == 0 ? p.kw : matA == 1 ? p.vw : p.rw) + (size_t)rmA * E;
    pf_row4k(W, wA, lane);
  }
  gload_lds16(p.ow + (size_t)rowB * E + kcB * 256 + lane * 4, wB);

  // x = LN0(emb[token])
  {
    float v = p.emb[(size_t)token * E + tid];
    float2 s = block_sum2(v, v * v, s_red);
    float m = s.x * (1.f / E), var = s.y * (1.f / E) - m * m;
    s_x[tid] = (v - m) / sqrtf(var + LN_EPS) * p.ln0_w[tid] + p.ln0_b[tid];
  }
  __syncthreads();

  for (int l = 0; l < NLAYER; ++l) {
    const float* stl = p.st + (size_t)5 * l * E;
    float* ostl = out_st + (size_t)5 * l * E;
    const int par = l & 1;
    const unsigned tg = (unsigned)(l + 1);

    // ================ Phase A: LN1 + mix + k/v/r matvec ================
    // B(l) DMA: l==0 issued at init; else issued at end of previous iteration.
    float xv_;
    if (l > 0) xv_ = poll_tag(&tx[par * E + tid], (unsigned)l);
    else       xv_ = s_x[tid];
    {
      float2 s = block_sum2(xv_, xv_ * xv_, s_red);
      float m = s.x * (1.f / E), var = s.y * (1.f / E) - m * m;
      float xn = (xv_ - m) / sqrtf(var + LN_EPS) * p.ln1_w[l * E + tid] + p.ln1_b[l * E + tid];
      float ax = stl[E + tid];
      float tk_ = p.tmk[l * E + tid], tv_ = p.tmv[l * E + tid], tr_ = p.tmr[l * E + tid];
      s_x[tid]  = xv_;
      s_xk[tid] = xn * tk_ + ax * (1.f - tk_);
      s_xv[tid] = xn * tv_ + ax * (1.f - tv_);
      s_xr[tid] = xn * tr_ + ax * (1.f - tr_);
      if (bid == 0) ostl[E + tid] = xn;            // new att_x
    }
    __syncthreads();
    wait_pf();                                      // A + B resident
    if (hasA) {
      const float* vec = (matA == 0) ? s_xk : (matA == 1) ? s_xv : s_xr;
      float dres = dotlds(wA, vec, lane);
      if (lane == 0) {
        u64* dst = (matA == 0 ? tk : matA == 1 ? tv : tr) + par * E + rmA;
        stg_tag(dst, (matA == 2) ? 1.f / (1.f + expf(-dres)) : dres, tg);
      }
    }

    // ================ Phase B: WKV + ow matvec ================
    // issue C (fkw) DMA into R1 (own wave region; own A-dot already done)
    pf_row4k(p.fkw + (size_t)l * H * E + (size_t)gw * E, wA, lane);
    {
      float kk, vv, rr;
      poll3(&tk[par * E + tid], &tv[par * E + tid], &tr[par * E + tid], tg, kk, vv, rr);
      float aav = stl[2 * E + tid], bbv = stl[3 * E + tid], ppv = stl[4 * E + tid];
      float tfv = p.tf[l * E + tid], tdv = p.td[l * E + tid];
      float wwv = tfv + kk;
      float pm = fmaxf(ppv, wwv);
      float e1 = expf(ppv - pm), e2 = expf(wwv - pm);
      float a = e1 * aav + e2 * vv, b = e1 * bbv + e2;
      s_wkv[tid] = rr * a / b;
      float ww2 = ppv + tdv;
      float p2 = fmaxf(ww2, kk);
      float f1 = expf(ww2 - p2), f2 = expf(kk - p2);
      if (bid == 0) {
        ostl[2 * E + tid] = f1 * aav + f2 * vv;     // naa
        ostl[3 * E + tid] = f1 * bbv + f2;          // nbb
        ostl[4 * E + tid] = p2;                     // npp
      }
    }
    __syncthreads();
    {
      const float4* v4 = (const float4*)(s_wkv + kcB * 256);
      const float4* w4 = (const float4*)wB;         // resident since phase A's wait
      float acc = warp_sum(dot4(w4[lane], v4[lane]));
      if (lane == 0) s_part[wid] = acc;
    }
    __syncthreads();
    if (tid < 4) {
      int r2i = bid * 4 + tid;
      float dsum = s_part[tid * 4] + s_part[tid * 4 + 1] +
                   s_part[tid * 4 + 2] + s_part[tid * 4 + 3];
      stg_tag(&tsx[par * E + r2i], s_x[r2i] + dsum, tg);
    }

    // ================ Phase C: LN2 + mix + fkw/frw matvecs ================
    {
      float sxv = poll_tag(&tsx[par * E + tid], tg);
      s_sx[tid] = sxv;
      float2 s = block_sum2(sxv, sxv * sxv, s_red);
      float m = s.x * (1.f / E), var = s.y * (1.f / E) - m * m;
      float xn2 = (sxv - m) / sqrtf(var + LN_EPS) * p.ln2_w[l * E + tid] + p.ln2_b[l * E + tid];
      float fx = stl[tid];
      float ftk = p.ftmk[l * E + tid], ftr = p.ftmr[l * E + tid];
      s_fxk[tid] = xn2 * ftk + fx * (1.f - ftk);
      s_fxr[tid] = xn2 * ftr + fx * (1.f - ftr);
      if (bid == 0) ostl[tid] = xn2;                // new ffn_x
    }
    __syncthreads();       // all waves past phase B; fxk/fxr visible
    wait_pf();                                      // C (fkw) resident
    // issue D (fvw) DMA into R2 (overwrites B region; B consumed by all waves)
    pf_row4k(p.fvw + (size_t)l * E * H + (size_t)rowD * H + kcD * 1024, wD, lane);
    {
      float dres = dotlds(wA, s_fxk, lane);
      if (lane == 0) { float t = fmaxf(dres, 0.f); stg_tag(&tfk[par * H + gw], t * t, tg); }
      if (wid >= 12) {   // frw: direct global streaming, rows bid*4 + (wid-12)
        const float* Wr = p.frw + (size_t)l * E * E + (size_t)(bid * 4 + wid - 12) * E;
        float dr2 = dot1024(Wr, s_fxr, lane);
        if (lane == 0) s_fr[wid - 12] = 1.f / (1.f + expf(-dr2));
      }
    }

    // ================ Phase D: fvw matvec + residual ================
    {
      const u64* base = tfk + par * H;
      u64 w0 = ld_tag(base + tid);
      u64 w1 = ld_tag(base + tid + 1024);
      u64 w2 = ld_tag(base + tid + 2048);
      u64 w3 = ld_tag(base + tid + 3072);
      while ((unsigned)w0 != tg) { __builtin_amdgcn_s_sleep(2); w0 = ld_tag(base + tid); }
      while ((unsigned)w1 != tg) { __builtin_amdgcn_s_sleep(2); w1 = ld_tag(base + tid + 1024); }
      while ((unsigned)w2 != tg) { __builtin_amdgcn_s_sleep(2); w2 = ld_tag(base + tid + 2048); }
      while ((unsigned)w3 != tg) { __builtin_amdgcn_s_sleep(2); w3 = ld_tag(base + tid + 3072); }
      // poll success implies all blocks' fkw dots stored => s_fxk reads done
      s_fk[tid]        = __uint_as_float((unsigned)(w0 >> 32));
      s_fk[tid + 1024] = __uint_as_float((unsigned)(w1 >> 32));
      s_fk[tid + 2048] = __uint_as_float((unsigned)(w2 >> 32));
      s_fk[tid + 3072] = __uint_as_float((unsigned)(w3 >> 32));
    }
    __syncthreads();       // all waves past phase C (frw done, R1 reads done)
    wait_pf();                                      // D resident
    // issue next layer's A DMA into R1
    if (l + 1 < NLAYER && hasA) {
      const float* W = (matA == 0 ? p.kw : matA == 1 ? p.vw : p.rw) +
                       (size_t)(l + 1) * E * E + (size_t)rmA * E;
      pf_row4k(W, wA, lane);
    }
    {
      const float4* v4 = (const float4*)(s_fk + kcD * 1024);
      const float4* w4 = (const float4*)wD;
      float acc = 0.f;
#pragma unroll
      for (int pc = 0; pc < 4; ++pc)
        acc += dot4(w4[lane + pc * 64], v4[lane + pc * 64]);
      acc = warp_sum(acc);
      if (lane == 0) s_part[wid] = acc;
    }
    __syncthreads();       // all waves done reading R2 (D) and s_fk
    if (tid < 4) {
      int r2i = bid * 4 + tid;
      float dsum = s_part[tid * 4] + s_part[tid * 4 + 1] +
                   s_part[tid * 4 + 2] + s_part[tid * 4 + 3];
      stg_tag(&tx[((l + 1) & 1) * E + r2i], s_sx[r2i] + s_fr[tid] * dsum, tg);
    }
    // issue next layer's B DMA into R2 front (safe: past the syncthreads above)
    if (l + 1 < NLAYER)
      gload_lds16(p.ow + (size_t)(l + 1) * E * E + (size_t)rowB * E + kcB * 256 + lane * 4, wB);
  }

  // ================ Head: LN_out + V x E matvec ================
  {
    float xv_ = poll_tag(&tx[(NLAYER & 1) * E + tid], (unsigned)NLAYER);
    float2 s = block_sum2(xv_, xv_ * xv_, s_red);
    float m = s.x * (1.f / E), var = s.y * (1.f / E) - m * m;
    s_xk[tid] = (xv_ - m) / sqrtf(var + LN_EPS) * p.lnow[tid] + p.lnob[tid];
  }
  __syncthreads();
  for (int row = gw; row < V; row += NWAVE) {
    const float* Wr = p.headw + (size_t)row * E;
    float dres = dot1024(Wr, s_xk, lane);
    if (lane == 0) p.out[row] = dres;
  }
}

extern "C" void kernel_launch(void* const* d_in, const int* in_sizes, int n_in,
                              void* d_out, int out_size, void* d_ws, size_t ws_size,
                              hipStream_t stream) {
  Params p;
  p.emb   = (const float*)d_in[0];
  p.ln0_w = (const float*)d_in[1];
  p.ln0_b = (const float*)d_in[2];
  p.ln1_w = (const float*)d_in[3];
  p.ln1_b = (const float*)d_in[4];
  p.tmk   = (const float*)d_in[5];
  p.tmv   = (const float*)d_in[6];
  p.tmr   = (const float*)d_in[7];
  p.tf    = (const float*)d_in[8];
  p.td    = (const float*)d_in[9];
  p.kw    = (const float*)d_in[10];
  p.vw    = (const float*)d_in[11];
  p.rw    = (const float*)d_in[12];
  p.ow    = (const float*)d_in[13];
  p.ln2_w = (const float*)d_in[14];
  p.ln2_b = (const float*)d_in[15];
  p.ftmk  = (const float*)d_in[16];
  p.ftmr  = (const float*)d_in[17];
  p.fkw   = (const float*)d_in[18];
  p.fvw   = (const float*)d_in[19];
  p.frw   = (const float*)d_in[20];
  p.lnow  = (const float*)d_in[21];
  p.lnob  = (const float*)d_in[22];
  p.headw = (const float*)d_in[23];
  if (in_sizes[24] == 1) {
    p.tok = (const int*)d_in[24];
    p.st  = (const float*)d_in[25];
  } else {
    p.st  = (const float*)d_in[24];
    p.tok = (const int*)d_in[25];
  }
  p.out   = (float*)d_out;
  p.ws    = (float*)d_ws;

  // zero ALL tag words each launch (graph node): (10E + 2H) u64 = 147456 B
  hipMemsetAsync(d_ws, 0, (10 * E + 2 * H) * sizeof(unsigned long long), stream);

  void* args[] = { &p };
  hipLaunchCooperativeKernel((const void*)rwkv_kernel, dim3(NB), dim3(NT),
                             args, SMEM_FLOATS * sizeof(float), stream);
}

// Round 9
// 724.964 us; speedup vs baseline: 1.0125x; 1.0125x over previous
//
#include <hip/hip_runtime.h>

#define E 1024
#define H 4096
#define NLAYER 24
#define V 50277
#define NB 256
#define NT 1024
#define LN_EPS 1e-5f

typedef unsigned long long u64;

// ---- LDS float offsets (dynamic shared, ~156 KB) ----
// R1/R2 (64KB each) ping-pong by layer parity p=l&1:
//   R[p]  : A(l) rows [0:48K) -> D1(l) ; B(l) [48K:64K) -> D2(l)
//   R[1-p]: fkw(l) [0:64K) -> A(l+1) [0:48K) (+B(l+1) at next phase A)
#define R1O   0
#define R2O   16384
#define POOLO 32768   // 4096 floats: xk|xv|xr|wkv -> k|v|r|wkv -> fxk -> fk
#define SXO   36864   // 1024
#define SSXO  37888   // 1024
#define FXRO  38912   // 1024
#define REDO  39936   // 32
#define PARTO 39968   // 16
#define FRO   39984   // 4
#define SMEMF 39988

#define WAITVM(N) asm volatile("s_waitcnt vmcnt(" #N ")" ::: "memory")

struct Params {
  const float* emb;   const float* ln0_w; const float* ln0_b;
  const float* ln1_w; const float* ln1_b;
  const float* tmk;   const float* tmv;   const float* tmr;
  const float* tf;    const float* td;
  const float* kw;    const float* vw;    const float* rw;  const float* ow;
  const float* ln2_w; const float* ln2_b;
  const float* ftmk;  const float* ftmr;
  const float* fkw;   const float* fvw;   const float* frw;
  const float* lnow;  const float* lnob;  const float* headw;
  const float* st;    const int* tok;
  float* out; float* ws;
};

// ---- tagged 8-byte dataflow handoff (relaxed agent scope) ----
__device__ __forceinline__ void stg_tag(u64* p, float v, unsigned tag) {
  u64 w = ((u64)__float_as_uint(v) << 32) | (u64)tag;
  __hip_atomic_store(p, w, __ATOMIC_RELAXED, __HIP_MEMORY_SCOPE_AGENT);
}
__device__ __forceinline__ u64 ld_tag(const u64* p) {
  return __hip_atomic_load(p, __ATOMIC_RELAXED, __HIP_MEMORY_SCOPE_AGENT);
}

// zero-VGPR global->LDS DMA: 64 lanes x 16 B = 1 KB per call.
__device__ __forceinline__ void gload_lds16(const float* g, float* l) {
  __builtin_amdgcn_global_load_lds(
      (const __attribute__((address_space(1))) unsigned int*)(g),
      (__attribute__((address_space(3))) unsigned int*)(l), 16, 0, 0);
}

__device__ __forceinline__ float warp_sum(float v) {
#pragma unroll
  for (int off = 32; off; off >>= 1) v += __shfl_down(v, off);
  return v;
}

// fused (sum, sumsq) block reduction; red = 32-float LDS scratch
__device__ float2 block_sum2(float a, float b, float* red) {
#pragma unroll
  for (int off = 32; off; off >>= 1) { a += __shfl_xor(a, off); b += __shfl_xor(b, off); }
  const int wid = threadIdx.x >> 6, lane = threadIdx.x & 63;
  if (lane == 0) { red[wid] = a; red[16 + wid] = b; }
  __syncthreads();
  if (wid == 0) {
    float s1 = (lane < 16) ? red[lane] : 0.f;
    float s2 = (lane < 16) ? red[16 + lane] : 0.f;
#pragma unroll
    for (int off = 8; off; off >>= 1) { s1 += __shfl_down(s1, off); s2 += __shfl_down(s2, off); }
    if (lane == 0) { red[0] = s1; red[16] = s2; }
  }
  __syncthreads();
  return make_float2(red[0], red[16]);
}

__device__ __forceinline__ float dot4(float4 a, float4 b) {
  return a.x * b.x + a.y * b.y + a.z * b.z + a.w * b.w;
}

__device__ __forceinline__ float dotlds(const float* wrow, const float* vec, int lane) {
  const float4* w4 = (const float4*)wrow;
  const float4* v4 = (const float4*)vec;
  float acc = 0.f;
#pragma unroll
  for (int p = 0; p < 4; ++p)
    acc += dot4(w4[lane + p * 64], v4[lane + p * 64]);
  return warp_sum(acc);
}

__device__ __forceinline__ float dot1024(const float* __restrict__ Wrow,
                                         const float* vec, int lane) {
  const float4* W4 = (const float4*)Wrow;
  const float4* v4 = (const float4*)vec;
  float acc = 0.f;
#pragma unroll
  for (int p = 0; p < 4; ++p)
    acc += dot4(W4[lane + p * 64], v4[lane + p * 64]);
  return warp_sum(acc);
}

__global__ __launch_bounds__(NT, 1) void rwkv_kernel(Params p) {
  const int tid = threadIdx.x, bid = blockIdx.x;
  const int lane = tid & 63, wid = tid >> 6;

  extern __shared__ float smem[];
  float* pool  = smem + POOLO;
  float* s_x   = smem + SXO;
  float* s_sx  = smem + SSXO;
  float* s_fxr = smem + FXRO;
  float* s_red = smem + REDO;
  float* s_part= smem + PARTO;
  float* s_fr  = smem + FRO;

  u64* tws = (u64*)p.ws;
  u64* tk  = tws;             // [2][E]
  u64* tv  = tws + 2 * E;
  u64* tr  = tws + 4 * E;
  u64* tsx = tws + 6 * E;
  u64* tx  = tws + 8 * E;
  u64* tfk = tws + 10 * E;    // [2][H]

  float* out_st = p.out + V;
  const int token = p.tok[0];

  const int e4 = wid;                  // engine id (wid<4)
  const bool isEng = wid < 4;          // DMA engines: counted-vmcnt only
  const bool isPol = wid >= 12;        // pollers: DMA-free waves
  const int pw = wid - 12;

  // ---- initial: engines issue A(0) into R1 ----
  if (isEng) {
#pragma unroll
    for (int j = 0; j < 3; ++j) {
      int r = bid * 12 + 3 * e4 + j;
      int mat = r >> 10, rm = r & (E - 1);
      const float* src = (mat == 0 ? p.kw : mat == 1 ? p.vw : p.rw) + (size_t)rm * E;
      float* dst = smem + R1O + (3 * e4 + j) * 1024;
#pragma unroll
      for (int c = 0; c < 4; ++c)
        gload_lds16(src + c * 256 + lane * 4, dst + c * 256);
    }
  }

  // LN0
  {
    float v = p.emb[(size_t)token * E + tid];
    float2 s = block_sum2(v, v * v, s_red);
    float m = s.x * (1.f / E), var = s.y * (1.f / E) - m * m;
    s_x[tid] = (v - m) / sqrtf(var + LN_EPS) * p.ln0_w[tid] + p.ln0_b[tid];
  }
  __syncthreads();

  for (int l = 0; l < NLAYER; ++l) {
    const float* stl = p.st + (size_t)5 * l * E;
    float* ostl = out_st + (size_t)5 * l * E;
    const int par = l & 1;
    const unsigned tg = (unsigned)(l + 1);
    float* Rp = smem + (par ? R2O : R1O);   // A/B/D regions this layer
    float* Rq = smem + (par ? R1O : R2O);   // fkw this layer / A next layer

    // ================ Phase A: LN1 + mix + k/v/r matvec ================
    __syncthreads();  // close prev fvw-dot reads of Rq before fkw DMA
    if (isEng) {
      // B(l): ow row bid*4+e, 4KB -> Rp[48K + e*4K)
      {
        const float* src = p.ow + (size_t)l * E * E + (size_t)(bid * 4 + e4) * E;
        float* dst = Rp + 12288 + e4 * 1024;
#pragma unroll
        for (int c = 0; c < 4; ++c) gload_lds16(src + c * 256 + lane * 4, dst + c * 256);
      }
      // fkw(l): rows bid*16+4e..+3 -> Rq
#pragma unroll
      for (int k = 0; k < 4; ++k) {
        const float* src = p.fkw + (size_t)l * H * E + (size_t)(bid * 16 + 4 * e4 + k) * E;
        float* dst = Rq + (4 * e4 + k) * 1024;
#pragma unroll
        for (int c = 0; c < 4; ++c) gload_lds16(src + c * 256 + lane * 4, dst + c * 256);
      }
      WAITVM(20);      // >=20 newer than A(l) -> A(l) resident
    }
    if (isPol && l > 0) {
      const u64* base = tx + par * E;
#pragma unroll
      for (int i = 0; i < 4; ++i) {
        int e = pw * 256 + i * 64 + lane;
        u64 w = ld_tag(base + e);
        while ((unsigned)w != (unsigned)l) { __builtin_amdgcn_s_sleep(1); w = ld_tag(base + e); }
        s_x[e] = __uint_as_float((unsigned)(w >> 32));
      }
    }
    __syncthreads();  // s_x ready + A(l)/B(l) path gated
    {
      float xv_ = s_x[tid];
      float2 s = block_sum2(xv_, xv_ * xv_, s_red);
      float m = s.x * (1.f / E), var = s.y * (1.f / E) - m * m;
      float xn = (xv_ - m) / sqrtf(var + LN_EPS) * p.ln1_w[l * E + tid] + p.ln1_b[l * E + tid];
      float ax = stl[E + tid];
      float a = p.tmk[l * E + tid], b = p.tmv[l * E + tid], c = p.tmr[l * E + tid];
      pool[tid]        = xn * a + ax * (1.f - a);   // xk
      pool[1024 + tid] = xn * b + ax * (1.f - b);   // xv
      pool[2048 + tid] = xn * c + ax * (1.f - c);   // xr
      if (bid == 0) ostl[E + tid] = xn;             // new att_x
    }
    __syncthreads();
    if (wid < 12) {
      int r = bid * 12 + wid;
      int mat = r >> 10, rm = r & (E - 1);
      float d = dotlds(Rp + wid * 1024, pool + mat * 1024, lane);
      if (lane == 0) {
        u64* dst = (mat == 0 ? tk : mat == 1 ? tv : tr) + par * E + rm;
        stg_tag(dst, mat == 2 ? 1.f / (1.f + expf(-d)) : d, tg);
      }
    }

    // ================ Phase B: WKV + ow matvec ================
    __syncthreads();  // close A-dots before D1 overwrites Rp[0:48K)
    if (isEng) {
#pragma unroll
      for (int c = 0; c < 12; ++c) {      // D1: fvw row bid*4+e chunks 0..11
        const float* src = p.fvw + (size_t)l * E * H + (size_t)(bid * 4 + e4) * H + c * 256;
        gload_lds16(src + lane * 4, Rp + e4 * 3072 + c * 256);
      }
      WAITVM(28);      // fkw16 + D1_12 newer than B -> B resident
    }
    if (isPol) {
      const u64 *bk = tk + par * E, *bv = tv + par * E, *br = tr + par * E;
#pragma unroll
      for (int i = 0; i < 4; ++i) {
        int e = pw * 256 + i * 64 + lane;
        u64 wk = ld_tag(bk + e), wv = ld_tag(bv + e), wr = ld_tag(br + e);
        while ((unsigned)wk != tg) { __builtin_amdgcn_s_sleep(1); wk = ld_tag(bk + e); }
        while ((unsigned)wv != tg) { __builtin_amdgcn_s_sleep(1); wv = ld_tag(bv + e); }
        while ((unsigned)wr != tg) { __builtin_amdgcn_s_sleep(1); wr = ld_tag(br + e); }
        pool[e]        = __uint_as_float((unsigned)(wk >> 32));  // k
        pool[1024 + e] = __uint_as_float((unsigned)(wv >> 32));  // v
        pool[2048 + e] = __uint_as_float((unsigned)(wr >> 32));  // r
      }
    }
    __syncthreads();
    {
      float kk = pool[tid], vv = pool[1024 + tid], rr = pool[2048 + tid];
      float aav = stl[2 * E + tid], bbv = stl[3 * E + tid], ppv = stl[4 * E + tid];
      float tfv = p.tf[l * E + tid], tdv = p.td[l * E + tid];
      float wwv = tfv + kk;
      float pm = fmaxf(ppv, wwv);
      float e1 = expf(ppv - pm), e2 = expf(wwv - pm);
      float a = e1 * aav + e2 * vv, b = e1 * bbv + e2;
      pool[3072 + tid] = rr * a / b;                // wkv
      float ww2 = ppv + tdv;
      float p2 = fmaxf(ww2, kk);
      float f1 = expf(ww2 - p2), f2 = expf(kk - p2);
      if (bid == 0) {
        ostl[2 * E + tid] = f1 * aav + f2 * vv;     // naa
        ostl[3 * E + tid] = f1 * bbv + f2;          // nbb
        ostl[4 * E + tid] = p2;                     // npp
      }
    }
    __syncthreads();
    {
      int rloc = wid >> 2, kc = wid & 3;
      const float4* w4 = (const float4*)(Rp + 12288 + rloc * 1024 + kc * 256);
      const float4* v4 = (const float4*)(pool + 3072 + kc * 256);
      float acc = warp_sum(dot4(w4[lane], v4[lane]));
      if (lane == 0) s_part[wid] = acc;
    }
    __syncthreads();
    if (tid < 4) {
      float dsum = s_part[tid * 4] + s_part[tid * 4 + 1] +
                   s_part[tid * 4 + 2] + s_part[tid * 4 + 3];
      stg_tag(&tsx[par * E + bid * 4 + tid], s_x[bid * 4 + tid] + dsum, tg);
    }

    // ================ Phase C: LN2 + mix + fkw/frw matvecs ================
    __syncthreads();  // close ow-dot reads of Rp[48K:64K) before D2
    if (isEng) {
#pragma unroll
      for (int c = 12; c < 16; ++c) {     // D2: fvw chunks 12..15 into B slots
        const float* src = p.fvw + (size_t)l * E * H + (size_t)(bid * 4 + e4) * H + c * 256;
        gload_lds16(src + lane * 4, Rp + 12288 + e4 * 1024 + (c - 12) * 256);
      }
      WAITVM(16);      // D1_12 + D2_4 newer than fkw -> fkw resident
    }
    if (isPol) {
      const u64* base = tsx + par * E;
#pragma unroll
      for (int i = 0; i < 4; ++i) {
        int e = pw * 256 + i * 64 + lane;
        u64 w = ld_tag(base + e);
        while ((unsigned)w != tg) { __builtin_amdgcn_s_sleep(1); w = ld_tag(base + e); }
        s_sx[e] = __uint_as_float((unsigned)(w >> 32));
      }
    }
    __syncthreads();
    {
      float sxv = s_sx[tid];
      float2 s = block_sum2(sxv, sxv * sxv, s_red);
      float m = s.x * (1.f / E), var = s.y * (1.f / E) - m * m;
      float xn2 = (sxv - m) / sqrtf(var + LN_EPS) * p.ln2_w[l * E + tid] + p.ln2_b[l * E + tid];
      float fx = stl[tid];
      float a = p.ftmk[l * E + tid], b = p.ftmr[l * E + tid];
      pool[tid]  = xn2 * a + fx * (1.f - a);        // fxk
      s_fxr[tid] = xn2 * b + fx * (1.f - b);
      if (bid == 0) ostl[tid] = xn2;                // new ffn_x
    }
    __syncthreads();
    {
      float d = dotlds(Rq + wid * 1024, pool, lane);
      if (lane == 0) { float t = fmaxf(d, 0.f); stg_tag(&tfk[par * H + bid * 16 + wid], t * t, tg); }
    }
    if (wid >= 8 && wid < 12) {   // frw: direct global stream (hidden under fk poll)
      const float* Wr = p.frw + (size_t)l * E * E + (size_t)(bid * 4 + wid - 8) * E;
      float d = dot1024(Wr, s_fxr, lane);
      if (lane == 0) s_fr[wid - 8] = 1.f / (1.f + expf(-d));
    }

    // ================ Phase D: fvw matvec + residual ================
    __syncthreads();  // close fkw-dot reads of Rq + pool reads before overwrite
    if (isEng) {
      if (l + 1 < NLAYER) {
#pragma unroll
        for (int j = 0; j < 3; ++j) {     // A(l+1) into Rq[0:48K)
          int r = bid * 12 + 3 * e4 + j;
          int mat = r >> 10, rm = r & (E - 1);
          const float* src = (mat == 0 ? p.kw : mat == 1 ? p.vw : p.rw) +
                             (size_t)(l + 1) * E * E + (size_t)rm * E;
          float* dst = Rq + (3 * e4 + j) * 1024;
#pragma unroll
          for (int c = 0; c < 4; ++c) gload_lds16(src + c * 256 + lane * 4, dst + c * 256);
        }
        WAITVM(12);    // A'12 newer than D2 -> D resident
      } else {
        WAITVM(0);
      }
    }
    if (isPol) {
      const u64* base = tfk + par * H;
#pragma unroll
      for (int i = 0; i < 16; ++i) {
        int e = pw * 1024 + i * 64 + lane;
        u64 w = ld_tag(base + e);
        while ((unsigned)w != tg) { __builtin_amdgcn_s_sleep(1); w = ld_tag(base + e); }
        pool[e] = __uint_as_float((unsigned)(w >> 32));   // fk
      }
    }
    __syncthreads();
    {
      int rloc = wid >> 2, q = wid & 3;
      const float4* v4 = (const float4*)(pool + q * 1024);
      const float4* w4 = (const float4*)((q < 3) ? (Rp + rloc * 3072 + q * 1024)
                                                 : (Rp + 12288 + rloc * 1024));
      float acc = 0.f;
#pragma unroll
      for (int pc = 0; pc < 4; ++pc)
        acc += dot4(w4[lane + pc * 64], v4[lane + pc * 64]);
      acc = warp_sum(acc);
      if (lane == 0) s_part[wid] = acc;
    }
    __syncthreads();
    if (tid < 4) {
      float dsum = s_part[tid * 4] + s_part[tid * 4 + 1] +
                   s_part[tid * 4 + 2] + s_part[tid * 4 + 3];
      stg_tag(&tx[((l + 1) & 1) * E + bid * 4 + tid],
              s_sx[bid * 4 + tid] + s_fr[tid] * dsum, tg);
    }
  }

  // ================ Head: LN_out + V x E matvec ================
  if (isPol) {
    const u64* base = tx + (NLAYER & 1) * E;
#pragma unroll
    for (int i = 0; i < 4; ++i) {
      int e = pw * 256 + i * 64 + lane;
      u64 w = ld_tag(base + e);
      while ((unsigned)w != (unsigned)NLAYER) { __builtin_amdgcn_s_sleep(1); w = ld_tag(base + e); }
      s_x[e] = __uint_as_float((unsigned)(w >> 32));
    }
  }
  __syncthreads();
  {
    float xv_ = s_x[tid];
    float2 s = block_sum2(xv_, xv_ * xv_, s_red);
    float m = s.x * (1.f / E), var = s.y * (1.f / E) - m * m;
    pool[tid] = (xv_ - m) / sqrtf(var + LN_EPS) * p.lnow[tid] + p.lnob[tid];
  }
  __syncthreads();
  {
    const int gw = bid * 16 + wid;
    for (int row = gw; row < V; row += 4096) {
      float d = dot1024(p.headw + (size_t)row * E, pool, lane);
      if (lane == 0) p.out[row] = d;
    }
  }
}

extern "C" void kernel_launch(void* const* d_in, const int* in_sizes, int n_in,
                              void* d_out, int out_size, void* d_ws, size_t ws_size,
                              hipStream_t stream) {
  Params p;
  p.emb   = (const float*)d_in[0];
  p.ln0_w = (const float*)d_in[1];
  p.ln0_b = (const float*)d_in[2];
  p.ln1_w = (const float*)d_in[3];
  p.ln1_b = (const float*)d_in[4];
  p.tmk   = (const float*)d_in[5];
  p.tmv   = (const float*)d_in[6];
  p.tmr   = (const float*)d_in[7];
  p.tf    = (const float*)d_in[8];
  p.td    = (const float*)d_in[9];
  p.kw    = (const float*)d_in[10];
  p.vw    = (const float*)d_in[11];
  p.rw    = (const float*)d_in[12];
  p.ow    = (const float*)d_in[13];
  p.ln2_w = (const float*)d_in[14];
  p.ln2_b = (const float*)d_in[15];
  p.ftmk  = (const float*)d_in[16];
  p.ftmr  = (const float*)d_in[17];
  p.fkw   = (const float*)d_in[18];
  p.fvw   = (const float*)d_in[19];
  p.frw   = (const float*)d_in[20];
  p.lnow  = (const float*)d_in[21];
  p.lnob  = (const float*)d_in[22];
  p.headw = (const float*)d_in[23];
  if (in_sizes[24] == 1) {
    p.tok = (const int*)d_in[24];
    p.st  = (const float*)d_in[25];
  } else {
    p.st  = (const float*)d_in[24];
    p.tok = (const int*)d_in[25];
  }
  p.out   = (float*)d_out;
  p.ws    = (float*)d_ws;

  // zero ALL tag words each launch (graph node): (10E + 2H) u64 = 147456 B
  hipMemsetAsync(d_ws, 0, (10 * E + 2 * H) * sizeof(unsigned long long), stream);

  void* args[] = { &p };
  hipLaunchCooperativeKernel((const void*)rwkv_kernel, dim3(NB), dim3(NT),
                             args, SMEMF * sizeof(float), stream);
}

// Round 10
// 579.192 us; speedup vs baseline: 1.2673x; 1.2517x over previous
//
#include <hip/hip_runtime.h>

#define E 1024
#define H 4096
#define NLAYER 24
#define V 50277
#define NB 256
#define NT 1024
#define LN_EPS 1e-5f

typedef unsigned long long u64;

// ---- LDS float offsets (dynamic shared, 160000 B) ----
// R1 (16 slots x 1024): A(l) rows 0-11 -> fkw(l) all 16 -> A(l+1) rows 0-11
// R2 (16 slots x 1024): fvw(l), slot w = row (w>>2), chunk (w&3) -- wave-private
#define R1O    0
#define R2O    16384
#define POOLO  32768   // 4096: xk|xv|xr|- (A); k|v|r|wkv (B); fxk (C); fk (D)
#define SXO    36864   // 1024
#define SSXO   37888   // 1024
#define FXRO   38912   // 1024
#define REDO   39936   // 32
#define PARTO  39968   // 16
#define PART2O 39984   // 16
#define SMEMF  40000

struct Params {
  const float* emb;   const float* ln0_w; const float* ln0_b;
  const float* ln1_w; const float* ln1_b;
  const float* tmk;   const float* tmv;   const float* tmr;
  const float* tf;    const float* td;
  const float* kw;    const float* vw;    const float* rw;  const float* ow;
  const float* ln2_w; const float* ln2_b;
  const float* ftmk;  const float* ftmr;
  const float* fkw;   const float* fvw;   const float* frw;
  const float* lnow;  const float* lnob;  const float* headw;
  const float* st;    const int* tok;
  float* out; float* ws;
};

// ---- tagged 8-byte dataflow handoff (relaxed agent scope) ----
__device__ __forceinline__ void stg_tag(u64* p, float v, unsigned tag) {
  u64 w = ((u64)__float_as_uint(v) << 32) | (u64)tag;
  __hip_atomic_store(p, w, __ATOMIC_RELAXED, __HIP_MEMORY_SCOPE_AGENT);
}
__device__ __forceinline__ u64 ld_tag(const u64* p) {
  return __hip_atomic_load(p, __ATOMIC_RELAXED, __HIP_MEMORY_SCOPE_AGENT);
}
__device__ __forceinline__ float poll_tag(const u64* p, unsigned tag) {
  u64 w = ld_tag(p);
  while ((unsigned)w != tag) { __builtin_amdgcn_s_sleep(1); w = ld_tag(p); }
  return __uint_as_float((unsigned)(w >> 32));
}

// explicit drain (only needed where no poll precedes a DMA consumption)
__device__ __forceinline__ void wait_pf() {
  asm volatile("s_waitcnt vmcnt(0)" ::: "memory");
}

// zero-VGPR global->LDS DMA: 64 lanes x 16 B = 1 KB per call.
__device__ __forceinline__ void gload_lds16(const float* g, float* l) {
  __builtin_amdgcn_global_load_lds(
      (const __attribute__((address_space(1))) unsigned int*)(g),
      (__attribute__((address_space(3))) unsigned int*)(l), 16, 0, 0);
}
__device__ __forceinline__ void pf_row4k(const float* row, float* dst, int lane) {
#pragma unroll
  for (int c = 0; c < 4; ++c)
    gload_lds16(row + c * 256 + lane * 4, dst + c * 256);
}

__device__ __forceinline__ float warp_sum(float v) {
#pragma unroll
  for (int off = 32; off; off >>= 1) v += __shfl_down(v, off);
  return v;
}

// single-sync LN stats: all threads contribute (v, v*v); returns (mean, var)
__device__ __forceinline__ float2 ln_stats(float v, float* red) {
  float a = v, b = v * v;
#pragma unroll
  for (int off = 32; off; off >>= 1) { a += __shfl_xor(a, off); b += __shfl_xor(b, off); }
  const int wid = threadIdx.x >> 6, lane = threadIdx.x & 63;
  if (lane == 0) { red[2 * wid] = a; red[2 * wid + 1] = b; }
  __syncthreads();
  float s1 = 0.f, s2 = 0.f;
  const float2* r2 = (const float2*)red;
#pragma unroll
  for (int j = 0; j < 16; ++j) { float2 t = r2[j]; s1 += t.x; s2 += t.y; }  // LDS broadcast
  float m = s1 * (1.f / E);
  return make_float2(m, s2 * (1.f / E) - m * m);
}

__device__ __forceinline__ float dot4(float4 a, float4 b) {
  return a.x * b.x + a.y * b.y + a.z * b.z + a.w * b.w;
}

__device__ __forceinline__ float dotlds(const float* wrow, const float* vec, int lane) {
  const float4* w4 = (const float4*)wrow;
  const float4* v4 = (const float4*)vec;
  float acc = 0.f;
#pragma unroll
  for (int p = 0; p < 4; ++p)
    acc += dot4(w4[lane + p * 64], v4[lane + p * 64]);
  return warp_sum(acc);
}

__device__ __forceinline__ float dot1024(const float* __restrict__ Wrow,
                                         const float* vec, int lane) {
  const float4* W4 = (const float4*)Wrow;
  const float4* v4 = (const float4*)vec;
  float acc = 0.f;
#pragma unroll
  for (int p = 0; p < 4; ++p)
    acc += dot4(W4[lane + p * 64], v4[lane + p * 64]);
  return warp_sum(acc);
}

__global__ __launch_bounds__(NT, 1) void rwkv_kernel(Params p) {
  const int tid = threadIdx.x, bid = blockIdx.x;
  const int lane = tid & 63, wid = tid >> 6;

  extern __shared__ float smem[];
  float* r1     = smem + R1O;
  float* r2     = smem + R2O;
  float* pool   = smem + POOLO;
  float* s_x    = smem + SXO;
  float* s_sx   = smem + SSXO;
  float* s_fxr  = smem + FXRO;
  float* s_red  = smem + REDO;
  float* s_part = smem + PARTO;
  float* s_part2= smem + PART2O;

  u64* tws = (u64*)p.ws;
  u64* tk  = tws;             // [2][E]
  u64* tv  = tws + 2 * E;
  u64* tr  = tws + 4 * E;
  u64* tsx = tws + 6 * E;
  u64* tx  = tws + 8 * E;
  u64* tfk = tws + 10 * E;    // [2][H]

  float* out_st = p.out + V;
  const int token = p.tok[0];

  // wave->work mappings
  const bool hasA = wid < 12;
  const int rA = bid * 12 + wid;                 // k/v/r row id (0..3071)
  const int matA = rA >> 10, rmA = rA & (E - 1);
  const int rloc = wid >> 2, kc = wid & 3;       // ow/frw/fvw: row bid*4+rloc, chunk kc
  const int rowO = bid * 4 + rloc;
  float* wA = r1 + wid * 1024;                   // wave-private R1 slot
  float* wD = r2 + wid * 1024;                   // wave-private R2 slot

  // ---- init: A(0) DMA ----
  if (hasA) {
    const float* W = (matA == 0 ? p.kw : matA == 1 ? p.vw : p.rw) + (size_t)rmA * E;
    pf_row4k(W, wA, lane);
  }

  // LN0
  {
    float v = p.emb[(size_t)token * E + tid];
    float2 mv = ln_stats(v, s_red);
    s_x[tid] = (v - mv.x) / sqrtf(mv.y + LN_EPS) * p.ln0_w[tid] + p.ln0_b[tid];
  }

  for (int l = 0; l < NLAYER; ++l) {
    const float* stl = p.st + (size_t)5 * l * E;
    float* ostl = out_st + (size_t)5 * l * E;
    const int par = l & 1;
    const unsigned tg = (unsigned)(l + 1);

    // ================ Phase A: LN1 + mix + k/v/r matvec ================
    float xv_;
    if (l > 0) { xv_ = poll_tag(&tx[par * E + tid], (unsigned)l); s_x[tid] = xv_; }
    else       { xv_ = s_x[tid]; }
    {
      float2 mv = ln_stats(xv_, s_red);                       // SYNC 1
      float xn = (xv_ - mv.x) / sqrtf(mv.y + LN_EPS) * p.ln1_w[l * E + tid] + p.ln1_b[l * E + tid];
      float ax = stl[E + tid];
      float a = p.tmk[l * E + tid], b = p.tmv[l * E + tid], c = p.tmr[l * E + tid];
      pool[tid]        = xn * a + ax * (1.f - a);             // xk
      pool[1024 + tid] = xn * b + ax * (1.f - b);             // xv
      pool[2048 + tid] = xn * c + ax * (1.f - c);             // xr
      if (bid == 0) ostl[E + tid] = xn;                       // new att_x
    }
    __syncthreads();                                          // SYNC 2
    wait_pf();   // A rows resident (l=0: init DMA; l>0: drained by tx poll)
    if (hasA) {
      float d = dotlds(wA, pool + matA * 1024, lane);
      if (lane == 0) {
        u64* dst = (matA == 0 ? tk : matA == 1 ? tv : tr) + par * E + rmA;
        stg_tag(dst, matA == 2 ? 1.f / (1.f + expf(-d)) : d, tg);
      }
    }

    // ================ Phase B: WKV + ow matvec ================
    // ow chunk -> registers (oldest), then fkw DMA (1.5 phases ahead of use)
    float4 wow = ((const float4*)(p.ow + (size_t)l * E * E + (size_t)rowO * E + kc * 256))[lane];
    pf_row4k(p.fkw + (size_t)l * H * E + (size_t)(bid * 16 + wid) * E, wA, lane);
    {
      // poll own element of k/v/r (drains DMAs/loads as a side effect)
      const u64 *bk = tk + par * E + tid, *bv = tv + par * E + tid, *br = tr + par * E + tid;
      u64 wk = ld_tag(bk), wv = ld_tag(bv), wr = ld_tag(br);
      while ((unsigned)wk != tg) { __builtin_amdgcn_s_sleep(1); wk = ld_tag(bk); }
      while ((unsigned)wv != tg) { __builtin_amdgcn_s_sleep(1); wv = ld_tag(bv); }
      while ((unsigned)wr != tg) { __builtin_amdgcn_s_sleep(1); wr = ld_tag(br); }
      float kk = __uint_as_float((unsigned)(wk >> 32));
      float vv = __uint_as_float((unsigned)(wv >> 32));
      float rr = __uint_as_float((unsigned)(wr >> 32));
      float aav = stl[2 * E + tid], bbv = stl[3 * E + tid], ppv = stl[4 * E + tid];
      float tfv = p.tf[l * E + tid], tdv = p.td[l * E + tid];
      float wwv = tfv + kk;
      float pm = fmaxf(ppv, wwv);
      float e1 = expf(ppv - pm), e2 = expf(wwv - pm);
      float a = e1 * aav + e2 * vv, b = e1 * bbv + e2;
      pool[3072 + tid] = rr * a / b;                          // wkv
      float ww2 = ppv + tdv;
      float p2 = fmaxf(ww2, kk);
      float f1 = expf(ww2 - p2), f2 = expf(kk - p2);
      if (bid == 0) {
        ostl[2 * E + tid] = f1 * aav + f2 * vv;               // naa
        ostl[3 * E + tid] = f1 * bbv + f2;                    // nbb
        ostl[4 * E + tid] = p2;                               // npp
      }
    }
    __syncthreads();                                          // SYNC 3 (wkv ready)
    {
      const float4* v4 = (const float4*)(pool + 3072 + kc * 256);
      float acc = warp_sum(dot4(wow, v4[lane]));
      if (lane == 0) s_part[wid] = acc;
    }
    __syncthreads();                                          // SYNC 4
    if (tid < 4) {
      float dsum = s_part[tid * 4] + s_part[tid * 4 + 1] +
                   s_part[tid * 4 + 2] + s_part[tid * 4 + 3];
      stg_tag(&tsx[par * E + bid * 4 + tid], s_x[bid * 4 + tid] + dsum, tg);
    }

    // ================ Phase C: LN2 + mix + fkw matvec + frw partials ================
    {
      float sxv = poll_tag(&tsx[par * E + tid], tg);          // drains fkw DMA too
      s_sx[tid] = sxv;
      // issue frw register chunk + fvw DMA now (use is ~2 barriers later)
      float4 wfr = ((const float4*)(p.frw + (size_t)l * E * E + (size_t)rowO * E + kc * 256))[lane];
      pf_row4k(p.fvw + (size_t)l * E * H + (size_t)rowO * H + kc * 1024, wD, lane);
      float2 mv = ln_stats(sxv, s_red);                       // SYNC 5
      float xn2 = (sxv - mv.x) / sqrtf(mv.y + LN_EPS) * p.ln2_w[l * E + tid] + p.ln2_b[l * E + tid];
      float fx = stl[tid];
      float a = p.ftmk[l * E + tid], b = p.ftmr[l * E + tid];
      pool[tid]  = xn2 * a + fx * (1.f - a);                  // fxk
      s_fxr[tid] = xn2 * b + fx * (1.f - b);
      if (bid == 0) ostl[tid] = xn2;                          // new ffn_x
      __syncthreads();                                        // SYNC 6
      float d = dotlds(wA, pool, lane);                       // fkw row (resident)
      if (lane == 0) { float t = fmaxf(d, 0.f); stg_tag(&tfk[par * H + bid * 16 + wid], t * t, tg); }
      const float4* f4 = (const float4*)(s_fxr + kc * 256);
      float fp = warp_sum(dot4(wfr, f4[lane]));               // frw partial
      if (lane == 0) s_part2[wid] = fp;
    }

    // ================ Phase D: fvw matvec + residual ================
    // issue A(l+1) DMA first (R1 slot self-owned, fkw-dot done in program order)
    if (l + 1 < NLAYER && hasA) {
      const float* W = (matA == 0 ? p.kw : matA == 1 ? p.vw : p.rw) +
                       (size_t)(l + 1) * E * E + (size_t)rmA * E;
      pf_row4k(W, wA, lane);
    }
    __syncthreads();             // SYNC 7: close C's pool/s_fxr reads before relay
    {
      const u64* base = tfk + par * H;
      u64 w0 = ld_tag(base + tid);
      u64 w1 = ld_tag(base + tid + 1024);
      u64 w2 = ld_tag(base + tid + 2048);
      u64 w3 = ld_tag(base + tid + 3072);
      while ((unsigned)w0 != tg) { __builtin_amdgcn_s_sleep(1); w0 = ld_tag(base + tid); }
      while ((unsigned)w1 != tg) { __builtin_amdgcn_s_sleep(1); w1 = ld_tag(base + tid + 1024); }
      while ((unsigned)w2 != tg) { __builtin_amdgcn_s_sleep(1); w2 = ld_tag(base + tid + 2048); }
      while ((unsigned)w3 != tg) { __builtin_amdgcn_s_sleep(1); w3 = ld_tag(base + tid + 3072); }
      pool[tid]        = __uint_as_float((unsigned)(w0 >> 32));
      pool[tid + 1024] = __uint_as_float((unsigned)(w1 >> 32));
      pool[tid + 2048] = __uint_as_float((unsigned)(w2 >> 32));
      pool[tid + 3072] = __uint_as_float((unsigned)(w3 >> 32));
    }
    __syncthreads();             // SYNC 8: fk ready; fvw drained by the poll above
    {
      const float4* v4 = (const float4*)(pool + kc * 1024);
      const float4* w4 = (const float4*)wD;                   // own slot
      float acc = 0.f;
#pragma unroll
      for (int pc = 0; pc < 4; ++pc)
        acc += dot4(w4[lane + pc * 64], v4[lane + pc * 64]);
      acc = warp_sum(acc);
      if (lane == 0) s_part[wid] = acc;
    }
    __syncthreads();             // SYNC 9
    if (tid < 4) {
      float dsum = s_part[tid * 4] + s_part[tid * 4 + 1] +
                   s_part[tid * 4 + 2] + s_part[tid * 4 + 3];
      float frs  = s_part2[tid * 4] + s_part2[tid * 4 + 1] +
                   s_part2[tid * 4 + 2] + s_part2[tid * 4 + 3];
      float fr = 1.f / (1.f + expf(-frs));
      stg_tag(&tx[((l + 1) & 1) * E + bid * 4 + tid],
              s_sx[bid * 4 + tid] + fr * dsum, tg);
    }
  }

  // ================ Head: LN_out + V x E matvec ================
  {
    float xv_ = poll_tag(&tx[(NLAYER & 1) * E + tid], (unsigned)NLAYER);
    float2 mv = ln_stats(xv_, s_red);
    pool[tid] = (xv_ - mv.x) / sqrtf(mv.y + LN_EPS) * p.lnow[tid] + p.lnob[tid];
  }
  __syncthreads();
  {
    const int gw = bid * 16 + wid;
    for (int row = gw; row < V; row += 4096) {
      float d = dot1024(p.headw + (size_t)row * E, pool, lane);
      if (lane == 0) p.out[row] = d;
    }
  }
}

extern "C" void kernel_launch(void* const* d_in, const int* in_sizes, int n_in,
                              void* d_out, int out_size, void* d_ws, size_t ws_size,
                              hipStream_t stream) {
  Params p;
  p.emb   = (const float*)d_in[0];
  p.ln0_w = (const float*)d_in[1];
  p.ln0_b = (const float*)d_in[2];
  p.ln1_w = (const float*)d_in[3];
  p.ln1_b = (const float*)d_in[4];
  p.tmk   = (const float*)d_in[5];
  p.tmv   = (const float*)d_in[6];
  p.tmr   = (const float*)d_in[7];
  p.tf    = (const float*)d_in[8];
  p.td    = (const float*)d_in[9];
  p.kw    = (const float*)d_in[10];
  p.vw    = (const float*)d_in[11];
  p.rw    = (const float*)d_in[12];
  p.ow    = (const float*)d_in[13];
  p.ln2_w = (const float*)d_in[14];
  p.ln2_b = (const float*)d_in[15];
  p.ftmk  = (const float*)d_in[16];
  p.ftmr  = (const float*)d_in[17];
  p.fkw   = (const float*)d_in[18];
  p.fvw   = (const float*)d_in[19];
  p.frw   = (const float*)d_in[20];
  p.lnow  = (const float*)d_in[21];
  p.lnob  = (const float*)d_in[22];
  p.headw = (const float*)d_in[23];
  if (in_sizes[24] == 1) {
    p.tok = (const int*)d_in[24];
    p.st  = (const float*)d_in[25];
  } else {
    p.st  = (const float*)d_in[24];
    p.tok = (const int*)d_in[25];
  }
  p.out   = (float*)d_out;
  p.ws    = (float*)d_ws;

  // zero ALL tag words each launch (graph node): (10E + 2H) u64 = 147456 B
  hipMemsetAsync(d_ws, 0, (10 * E + 2 * H) * sizeof(unsigned long long), stream);

  void* args[] = { &p };
  hipLaunchCooperativeKernel((const void*)rwkv_kernel, dim3(NB), dim3(NT),
                             args, SMEMF * sizeof(float), stream);
}